// Round 1
// baseline (4476.849 us; speedup 1.0000x reference)
//
#include <hip/hip_runtime.h>
#include <math.h>

#define NU     32
#define HASHF  1024
#define BASISK 128
#define DD     12288
#define BN     16
#define DEPTH  16

#define KC_Y   32          // split-K chunks for Wt matmul (kchunk = 384)
#define KCH_Y  384
#define KC_H   128         // split-K chunks for P matmul (kchunk = 96)
#define KCH_H  96
#define LXF_LD 20          // padded LDS row stride (floats), 16B-aligned rows

// ---------------------------------------------------------------------------
// xfT[k][b] = x[b][k]
__global__ __launch_bounds__(256) void k_transpose(const float* __restrict__ x,
                                                   float* __restrict__ xfT) {
    int i = blockIdx.x * 256 + threadIdx.x;
    int b = i / DD, k = i % DD;
    xfT[(size_t)k * BN + b] = x[i];
}

// ---------------------------------------------------------------------------
// One-time: S[u] = B_u^T B_u  (128x128 per unit)
__global__ __launch_bounds__(128) void k_S(const float* __restrict__ basis,
                                           float* __restrict__ S) {
    int u  = blockIdx.x >> 3;
    int it = blockIdx.x & 7;
    int t  = threadIdx.x;
    int i0 = it * 16;

    __shared__ float lrow[8 * BASISK];
    float acc[16];
#pragma unroll
    for (int i = 0; i < 16; i++) acc[i] = 0.f;

    const float* bu = basis + (size_t)u * HASHF * BASISK;
    for (int fb = 0; fb < HASHF / 8; fb++) {
#pragma unroll
        for (int r = 0; r < 8; r++)
            lrow[r * BASISK + t] = bu[(size_t)(fb * 8 + r) * BASISK + t];
        __syncthreads();
#pragma unroll
        for (int r = 0; r < 8; r++) {
            float wj = lrow[r * BASISK + t];
#pragma unroll
            for (int i = 0; i < 16; i++)
                acc[i] += lrow[r * BASISK + i0 + i] * wj;
        }
        __syncthreads();
    }
#pragma unroll
    for (int i = 0; i < 16; i++)
        S[((size_t)u * BASISK + i0 + i) * BASISK + t] = acc[i];
}

// ---------------------------------------------------------------------------
// Prologue-only P matmul: h_part[c][f][b] from xfT
__global__ __launch_bounds__(256) void k_matP(const float* __restrict__ xfT,
                                              const float* __restrict__ P,
                                              float* __restrict__ h_part) {
    int nt = blockIdx.x & 1;
    int c  = blockIdx.x >> 1;
    int t  = threadIdx.x;
    int f0 = nt * 512 + t * 2;
    int kbase = c * KCH_H;

    __shared__ float lxf[KCH_H * BN];
    for (int j = t; j < KCH_H * BN; j += 256)
        lxf[j] = xfT[(size_t)kbase * BN + j];
    __syncthreads();

    float2 acc[BN];
#pragma unroll
    for (int b = 0; b < BN; b++) acc[b] = make_float2(0.f, 0.f);

    const float* wp = P + (size_t)kbase * HASHF + f0;
    for (int kl = 0; kl < KCH_H; kl += 8) {
        float2 w[8];
#pragma unroll
        for (int r = 0; r < 8; r++)
            w[r] = *(const float2*)(wp + (size_t)(kl + r) * HASHF);
#pragma unroll
        for (int r = 0; r < 8; r++) {
            const float4* xv = (const float4*)&lxf[(kl + r) * BN];
#pragma unroll
            for (int q = 0; q < 4; q++) {
                float4 a = xv[q];
                acc[4*q+0].x += a.x * w[r].x; acc[4*q+0].y += a.x * w[r].y;
                acc[4*q+1].x += a.y * w[r].x; acc[4*q+1].y += a.y * w[r].y;
                acc[4*q+2].x += a.z * w[r].x; acc[4*q+2].y += a.z * w[r].y;
                acc[4*q+3].x += a.w * w[r].x; acc[4*q+3].y += a.w * w[r].y;
            }
        }
    }
    float* hp = h_part + (size_t)c * (HASHF * BN) + (size_t)f0 * BN;
#pragma unroll
    for (int fi = 0; fi < 2; fi++) {
#pragma unroll
        for (int q = 0; q < 4; q++) {
            float4 v;
            v.x = fi ? acc[4*q+0].y : acc[4*q+0].x;
            v.y = fi ? acc[4*q+1].y : acc[4*q+1].x;
            v.z = fi ? acc[4*q+2].y : acc[4*q+2].x;
            v.w = fi ? acc[4*q+3].y : acc[4*q+3].x;
            *(float4*)&hp[fi * BN + q * 4] = v;
        }
    }
}

// ---------------------------------------------------------------------------
// Fused: blocks [0,128)  -> coeff partials + reduced h_full (from u2==0 blocks)
//        blocks [128,...) -> Wt matmul partials (the HBM stream; omitted at s=15)
__global__ __launch_bounds__(256) void k_big(const float* __restrict__ xfT,
                                             const float* __restrict__ Wt,
                                             float* __restrict__ y_part,
                                             const float* __restrict__ h_part,
                                             const float* __restrict__ basis,
                                             float* __restrict__ coeff_part,
                                             float* __restrict__ h_full) {
    __shared__ float smem[KCH_Y * BN];   // 24 KB
    int t = threadIdx.x;

    if (blockIdx.x < 128) {
        int u2 = blockIdx.x >> 3;
        int fc = blockIdx.x & 7;
        int u  = u2 * 2 + (t >> 7);
        int k  = t & 127;

        for (int j = t; j < 128 * BN; j += 256) {
            int fl = j >> 4, b = j & 15;
            float sum = 0.f;
            const float* hp = h_part + (size_t)(fc * 128 + fl) * BN + b;
#pragma unroll 4
            for (int c = 0; c < KC_H; c++) sum += hp[(size_t)c * (HASHF * BN)];
            smem[fl * BN + b] = sum;
            if (u2 == 0) h_full[(size_t)(fc * 128 + fl) * BN + b] = sum;
        }
        __syncthreads();

        float acc[BN];
#pragma unroll
        for (int b = 0; b < BN; b++) acc[b] = 0.f;
        const float* bp = basis + ((size_t)u * HASHF + fc * 128) * BASISK + k;
        for (int fl = 0; fl < 128; fl++) {
            float w = bp[(size_t)fl * BASISK];
            const float4* lv = (const float4*)&smem[fl * BN];
#pragma unroll
            for (int q = 0; q < 4; q++) {
                float4 a = lv[q];
                acc[4*q+0] += a.x * w;
                acc[4*q+1] += a.y * w;
                acc[4*q+2] += a.z * w;
                acc[4*q+3] += a.w * w;
            }
        }
#pragma unroll
        for (int b = 0; b < BN; b++)
            coeff_part[((size_t)(fc * BN + b) * NU + u) * BASISK + k] = acc[b];
    } else {
        int m  = blockIdx.x - 128;
        int nt = m % 24;
        int c  = m / 24;
        int n0 = nt * 512 + t * 2;
        int kbase = c * KCH_Y;

        for (int j = t; j < KCH_Y * BN; j += 256)
            smem[j] = xfT[(size_t)kbase * BN + j];
        __syncthreads();

        float2 acc[BN];
#pragma unroll
        for (int b = 0; b < BN; b++) acc[b] = make_float2(0.f, 0.f);

        const float* wp = Wt + (size_t)kbase * DD + n0;
        for (int kl = 0; kl < KCH_Y; kl += 8) {
            float2 w[8];
#pragma unroll
            for (int r = 0; r < 8; r++)
                w[r] = *(const float2*)(wp + (size_t)(kl + r) * DD);
#pragma unroll
            for (int r = 0; r < 8; r++) {
                const float4* xv = (const float4*)&smem[(kl + r) * BN];
#pragma unroll
                for (int q = 0; q < 4; q++) {
                    float4 a = xv[q];
                    acc[4*q+0].x += a.x * w[r].x; acc[4*q+0].y += a.x * w[r].y;
                    acc[4*q+1].x += a.y * w[r].x; acc[4*q+1].y += a.y * w[r].y;
                    acc[4*q+2].x += a.z * w[r].x; acc[4*q+2].y += a.z * w[r].y;
                    acc[4*q+3].x += a.w * w[r].x; acc[4*q+3].y += a.w * w[r].y;
                }
            }
        }
#pragma unroll
        for (int b = 0; b < BN; b++)
            *(float2*)&y_part[(size_t)c * (BN * DD) + (size_t)b * DD + n0] = acc[b];
    }
}

// ---------------------------------------------------------------------------
// mags[b][u] = c^T S_u c ; coeff_full write; masked atomicMax argmax into best[s][b]
// key = (float_bits(mag) << 6) | (31-u)  -> on ties, lowest u wins (matches ref)
__global__ __launch_bounds__(128) void k_magsmax(const float* __restrict__ coeff_part,
                                                 const float* __restrict__ S,
                                                 float* __restrict__ coeff_full,
                                                 unsigned long long* __restrict__ best,
                                                 const int* __restrict__ routes, int s) {
    int b = blockIdx.x >> 5;
    int u = blockIdx.x & 31;
    int t = threadIdx.x;

    __shared__ int s_used;
    __shared__ float lc[BASISK];
    __shared__ float red[BASISK];

    if (t == 0) {
        int used = 0;
        for (int j = 0; j < s; j++) used |= (routes[b * DEPTH + j] == u);
        s_used = used;
    }
    __syncthreads();
    if (s_used) return;

    float cv = 0.f;
#pragma unroll
    for (int fc = 0; fc < 8; fc++)
        cv += coeff_part[((size_t)(fc * BN + b) * NU + u) * BASISK + t];
    lc[t] = cv;
    coeff_full[((size_t)b * NU + u) * BASISK + t] = cv;
    __syncthreads();

    float v = 0.f;
    const float* Sp = S + (size_t)u * BASISK * BASISK + t;
#pragma unroll 8
    for (int i = 0; i < BASISK; i++) v += Sp[(size_t)i * BASISK] * lc[i];

    red[t] = v * cv;
    __syncthreads();
    for (int st = 64; st > 0; st >>= 1) {
        if (t < st) red[t] += red[t + st];
        __syncthreads();
    }
    if (t == 0) {
        float mag = fmaxf(red[0], 0.f);
        unsigned long long key =
            ((unsigned long long)__float_as_uint(mag) << 6) |
            (unsigned long long)(31 - u);
        atomicMax(best + (size_t)s * BN + b, key);
    }
}

// ---------------------------------------------------------------------------
// Fused tail:
//   blocks [0,nMatP): y-reduce + bias[sel] + tanh -> xfT_next + P-matmul partial
//   blocks [nMatP, nMatP+64): residual out_acc += h_full - B_sel c_sel; record route
__global__ __launch_bounds__(256) void k_tail(const float* __restrict__ y_part,
                                              const float* __restrict__ bias,
                                              const unsigned long long* __restrict__ best,
                                              const float* __restrict__ P,
                                              float* __restrict__ xfT_next,
                                              float* __restrict__ h_part,
                                              const float* __restrict__ h_full,
                                              const float* __restrict__ coeff_full,
                                              const float* __restrict__ basis,
                                              float* __restrict__ out_acc,
                                              int* __restrict__ routes,
                                              int s, int nMatP) {
    int t = threadIdx.x;

    if ((int)blockIdx.x < nMatP) {
        __shared__ float lxf[KCH_H * LXF_LD];   // 96*20*4 = 7.5 KB
        int nt = blockIdx.x & 1;
        int c  = blockIdx.x >> 1;
        int kbase = c * KCH_H;

        // stage: reduce y partials + bias + tanh, b-major for coalescing
        for (int j = t; j < KCH_H * BN; j += 256) {
            int b  = j / KCH_H;
            int fl = j - b * KCH_H;
            float sum = 0.f;
            const float* yp = y_part + (size_t)b * DD + kbase + fl;
#pragma unroll 4
            for (int cc = 0; cc < KC_Y; cc++) sum += yp[(size_t)cc * (BN * DD)];
            int u = 31 - (int)(best[(size_t)s * BN + b] & 63ull);
            float v = tanhf(sum + bias[(size_t)u * DD + kbase + fl]);
            lxf[fl * LXF_LD + b] = v;
            if (nt == (fl >= KCH_H / 2 ? 1 : 0))
                xfT_next[(size_t)(kbase + fl) * BN + b] = v;
        }
        __syncthreads();

        int f0 = nt * 512 + t * 2;
        float2 acc[BN];
#pragma unroll
        for (int b = 0; b < BN; b++) acc[b] = make_float2(0.f, 0.f);

        const float* wp = P + (size_t)kbase * HASHF + f0;
        for (int kl = 0; kl < KCH_H; kl += 8) {
            float2 w[8];
#pragma unroll
            for (int r = 0; r < 8; r++)
                w[r] = *(const float2*)(wp + (size_t)(kl + r) * HASHF);
#pragma unroll
            for (int r = 0; r < 8; r++) {
                const float4* xv = (const float4*)&lxf[(kl + r) * LXF_LD];
#pragma unroll
                for (int q = 0; q < 4; q++) {
                    float4 a = xv[q];
                    acc[4*q+0].x += a.x * w[r].x; acc[4*q+0].y += a.x * w[r].y;
                    acc[4*q+1].x += a.y * w[r].x; acc[4*q+1].y += a.y * w[r].y;
                    acc[4*q+2].x += a.z * w[r].x; acc[4*q+2].y += a.z * w[r].y;
                    acc[4*q+3].x += a.w * w[r].x; acc[4*q+3].y += a.w * w[r].y;
                }
            }
        }
        float* hp = h_part + (size_t)c * (HASHF * BN) + (size_t)f0 * BN;
#pragma unroll
        for (int fi = 0; fi < 2; fi++) {
#pragma unroll
            for (int q = 0; q < 4; q++) {
                float4 v;
                v.x = fi ? acc[4*q+0].y : acc[4*q+0].x;
                v.y = fi ? acc[4*q+1].y : acc[4*q+1].x;
                v.z = fi ? acc[4*q+2].y : acc[4*q+2].x;
                v.w = fi ? acc[4*q+3].y : acc[4*q+3].x;
                *(float4*)&hp[fi * BN + q * 4] = v;
            }
        }
    } else {
        int rid = blockIdx.x - nMatP;
        int b   = rid >> 2;
        int fq  = rid & 3;
        __shared__ float lc[BASISK];

        int u = 31 - (int)(best[(size_t)s * BN + b] & 63ull);
        if (t < BASISK) lc[t] = coeff_full[((size_t)b * NU + u) * BASISK + t];
        if (t == 0 && fq == 0) routes[b * DEPTH + s] = u;
        __syncthreads();

        int f = fq * 256 + t;
        float hv = h_full[(size_t)f * BN + b];
        const float4* br = (const float4*)&basis[((size_t)u * HASHF + f) * BASISK];
        const float4* cr = (const float4*)lc;
        float dot = 0.f;
#pragma unroll
        for (int j = 0; j < 32; j++) {
            float4 bv = br[j], c4 = cr[j];
            dot += bv.x * c4.x + bv.y * c4.y + bv.z * c4.z + bv.w * c4.w;
        }
        out_acc[b * HASHF + f] += hv - dot;
    }
}

// ---------------------------------------------------------------------------
__global__ __launch_bounds__(256) void k_out(const float* __restrict__ out_acc,
                                             const int* __restrict__ routes,
                                             float* __restrict__ o, int n) {
    int i = blockIdx.x * 256 + threadIdx.x;
    if (i >= n) return;
    if (i < BN * HASHF) o[i] = out_acc[i];
    else o[i] = (float)routes[i - BN * HASHF];
}

// ---------------------------------------------------------------------------
extern "C" void kernel_launch(void* const* d_in, const int* in_sizes, int n_in,
                              void* d_out, int out_size, void* d_ws, size_t ws_size,
                              hipStream_t stream) {
    const float* x     = (const float*)d_in[0];
    const float* P     = (const float*)d_in[1];
    const float* basis = (const float*)d_in[2];
    const float* Wt    = (const float*)d_in[3];
    const float* bias  = (const float*)d_in[4];
    float* out = (float*)d_out;

    float* w = (float*)d_ws;
    size_t off = 0;
    auto alloc = [&](size_t nf) { float* p = w + off; off += nf; return p; };

    float* xfT0       = alloc((size_t)DD * BN);
    float* xfT1       = alloc((size_t)DD * BN);
    float* out_acc    = alloc(BN * HASHF);
    unsigned long long* best = (unsigned long long*)alloc(DEPTH * BN * 2); // 8B each
    float* coeff_part = alloc((size_t)8 * BN * NU * BASISK);
    float* coeff_full = alloc((size_t)BN * NU * BASISK);
    float* h_full     = alloc((size_t)HASHF * BN);
    float* S          = alloc((size_t)NU * BASISK * BASISK);
    int*   routes     = (int*)alloc(BN * DEPTH);
    float* y_part     = alloc((size_t)KC_Y * BN * DD);
    float* h_part     = alloc((size_t)KC_H * BN * HASHF);
    (void)ws_size;

    // zero out_acc + best (contiguous)
    hipMemsetAsync(out_acc, 0,
                   (size_t)BN * HASHF * sizeof(float) +
                   (size_t)DEPTH * BN * sizeof(unsigned long long), stream);

    k_transpose<<<(BN * DD) / 256, 256, 0, stream>>>(x, xfT0);
    k_S<<<NU * 8, 128, 0, stream>>>(basis, S);
    k_matP<<<2 * KC_H, 256, 0, stream>>>(xfT0, P, h_part);

    for (int s = 0; s < DEPTH; s++) {
        float* cur = (s & 1) ? xfT1 : xfT0;
        float* nxt = (s & 1) ? xfT0 : xfT1;

        int nWt = (s < DEPTH - 1) ? 24 * KC_Y : 0;       // skip dead Wt stream at s=15
        k_big<<<128 + nWt, 256, 0, stream>>>(cur, Wt, y_part, h_part, basis,
                                             coeff_part, h_full);
        k_magsmax<<<BN * NU, 128, 0, stream>>>(coeff_part, S, coeff_full, best,
                                               routes, s);
        int nMatP = (s < DEPTH - 1) ? 2 * KC_H : 0;      // residual-only at s=15
        k_tail<<<nMatP + 64, 256, 0, stream>>>(y_part, bias, best, P, nxt, h_part,
                                               h_full, coeff_full, basis, out_acc,
                                               routes, s, nMatP);
    }

    k_out<<<(BN * HASHF + BN * DEPTH + 255) / 256, 256, 0, stream>>>(out_acc, routes,
                                                                     out, out_size);
}

// Round 2
// 3795.282 us; speedup vs baseline: 1.1796x; 1.1796x over previous
//
#include <hip/hip_runtime.h>
#include <math.h>

#define NU     32
#define HASHF  1024
#define BASISK 128
#define DD     12288
#define BN     16
#define DEPTH  16

#define KC_Y   32          // split-K chunks for Wt matmul (kchunk = 384)
#define KCH_Y  384
#define KC_H   64          // split-K chunks for P matmul (kchunk = 192)
#define KCH_H  192
#define LXF_LD 12          // padded LDS stride for [KCH_H][8] tiles (float4-aligned)
#define CSM_LD 20          // padded LDS stride for coeff [128][16] tiles (float4-aligned)

// ---------------------------------------------------------------------------
// xfT[k][b] = x[b][k]
__global__ __launch_bounds__(256) void k_transpose(const float* __restrict__ x,
                                                   float* __restrict__ xfT) {
    int i = blockIdx.x * 256 + threadIdx.x;
    int b = i / DD, k = i % DD;
    xfT[(size_t)k * BN + b] = x[i];
}

// ---------------------------------------------------------------------------
// One-time: S[u] = B_u^T B_u  (128x128 per unit)
__global__ __launch_bounds__(128) void k_S(const float* __restrict__ basis,
                                           float* __restrict__ S) {
    int u  = blockIdx.x >> 3;
    int it = blockIdx.x & 7;
    int t  = threadIdx.x;
    int i0 = it * 16;

    __shared__ float lrow[8 * BASISK];
    float acc[16];
#pragma unroll
    for (int i = 0; i < 16; i++) acc[i] = 0.f;

    const float* bu = basis + (size_t)u * HASHF * BASISK;
    for (int fb = 0; fb < HASHF / 8; fb++) {
#pragma unroll
        for (int r = 0; r < 8; r++)
            lrow[r * BASISK + t] = bu[(size_t)(fb * 8 + r) * BASISK + t];
        __syncthreads();
#pragma unroll
        for (int r = 0; r < 8; r++) {
            float wj = lrow[r * BASISK + t];
#pragma unroll
            for (int i = 0; i < 16; i++)
                acc[i] += lrow[r * BASISK + i0 + i] * wj;
        }
        __syncthreads();
    }
#pragma unroll
    for (int i = 0; i < 16; i++)
        S[((size_t)u * BASISK + i0 + i) * BASISK + t] = acc[i];
}

// ---------------------------------------------------------------------------
// Prologue-only P matmul: h_part[c][b][f] from xfT.
// grid = 2*KC_H blocks (c, bh); each block owns 8 exclusive b columns.
__global__ __launch_bounds__(256) void k_matP(const float* __restrict__ xfT,
                                              const float* __restrict__ P,
                                              float* __restrict__ h_part) {
    int bh = blockIdx.x & 1;
    int c  = blockIdx.x >> 1;
    int t  = threadIdx.x;
    int kbase = c * KCH_H;

    __shared__ __align__(16) float lxf[KCH_H * LXF_LD];
    for (int j = t; j < KCH_H * 8; j += 256) {
        int b_l = j & 7, fl = j >> 3;
        lxf[fl * LXF_LD + b_l] = xfT[(size_t)(kbase + fl) * BN + bh * 8 + b_l];
    }
    __syncthreads();

    int f0 = t * 4;
    float acc[8][4] = {};
    const float* wp = P + (size_t)kbase * HASHF + f0;
    for (int kl = 0; kl < KCH_H; kl++) {
        float4 w = *(const float4*)(wp + (size_t)kl * HASHF);
        const float4* xv = (const float4*)&lxf[kl * LXF_LD];
        float4 x0 = xv[0], x1 = xv[1];
        float xb[8] = {x0.x, x0.y, x0.z, x0.w, x1.x, x1.y, x1.z, x1.w};
#pragma unroll
        for (int b = 0; b < 8; b++) {
            acc[b][0] += xb[b] * w.x; acc[b][1] += xb[b] * w.y;
            acc[b][2] += xb[b] * w.z; acc[b][3] += xb[b] * w.w;
        }
    }
    float* hp = h_part + (size_t)c * (BN * HASHF) + (size_t)(bh * 8) * HASHF + f0;
#pragma unroll
    for (int b = 0; b < 8; b++)
        *(float4*)&hp[(size_t)b * HASHF] =
            make_float4(acc[b][0], acc[b][1], acc[b][2], acc[b][3]);
}

// ---------------------------------------------------------------------------
// Fused: blocks [0,128)  -> coeff partials + reduced h_full (u2==0 blocks)
//        blocks [128,...) -> Wt matmul partials (HBM stream; omitted at s=15)
__global__ __launch_bounds__(256) void k_big(const float* __restrict__ xfT,
                                             const float* __restrict__ Wt,
                                             float* __restrict__ y_part,
                                             const float* __restrict__ h_part,
                                             const float* __restrict__ basis,
                                             float* __restrict__ coeff_part,
                                             float* __restrict__ h_full) {
    __shared__ __align__(16) float smem[KCH_Y * BN];   // 24 KB (coeff path uses 10 KB)
    int t = threadIdx.x;

    if (blockIdx.x < 128) {
        int u2 = blockIdx.x >> 3;
        int fc = blockIdx.x & 7;
        int u  = u2 * 2 + (t >> 7);
        int k  = t & 127;

        // stage: reduce h_part over c for this fc chunk (b-major, coalesced runs)
        for (int j = t; j < 128 * BN; j += 256) {
            int b = j >> 7, fl = j & 127;
            float sum = 0.f;
            const float* hp = h_part + (size_t)b * HASHF + fc * 128 + fl;
#pragma unroll 4
            for (int c = 0; c < KC_H; c++) sum += hp[(size_t)c * (BN * HASHF)];
            smem[fl * CSM_LD + b] = sum;
            if (u2 == 0) h_full[(size_t)b * HASHF + fc * 128 + fl] = sum;
        }
        __syncthreads();

        float acc[BN];
#pragma unroll
        for (int b = 0; b < BN; b++) acc[b] = 0.f;
        const float* bp = basis + ((size_t)u * HASHF + fc * 128) * BASISK + k;
        for (int fl = 0; fl < 128; fl++) {
            float w = bp[(size_t)fl * BASISK];
            const float4* lv = (const float4*)&smem[fl * CSM_LD];
#pragma unroll
            for (int q = 0; q < 4; q++) {
                float4 a = lv[q];
                acc[4*q+0] += a.x * w;
                acc[4*q+1] += a.y * w;
                acc[4*q+2] += a.z * w;
                acc[4*q+3] += a.w * w;
            }
        }
#pragma unroll
        for (int b = 0; b < BN; b++)
            coeff_part[((size_t)(fc * BN + b) * NU + u) * BASISK + k] = acc[b];
    } else {
        int m  = blockIdx.x - 128;
        int nt = m % 24;
        int c  = m / 24;
        int n0 = nt * 512 + t * 2;
        int kbase = c * KCH_Y;

        for (int j = t; j < KCH_Y * BN; j += 256)
            smem[j] = xfT[(size_t)kbase * BN + j];
        __syncthreads();

        float2 acc[BN];
#pragma unroll
        for (int b = 0; b < BN; b++) acc[b] = make_float2(0.f, 0.f);

        const float* wp = Wt + (size_t)kbase * DD + n0;
        for (int kl = 0; kl < KCH_Y; kl += 8) {
            float2 w[8];
#pragma unroll
            for (int r = 0; r < 8; r++)
                w[r] = *(const float2*)(wp + (size_t)(kl + r) * DD);
#pragma unroll
            for (int r = 0; r < 8; r++) {
                const float4* xv = (const float4*)&smem[(kl + r) * BN];
#pragma unroll
                for (int q = 0; q < 4; q++) {
                    float4 a = xv[q];
                    acc[4*q+0].x += a.x * w[r].x; acc[4*q+0].y += a.x * w[r].y;
                    acc[4*q+1].x += a.y * w[r].x; acc[4*q+1].y += a.y * w[r].y;
                    acc[4*q+2].x += a.z * w[r].x; acc[4*q+2].y += a.z * w[r].y;
                    acc[4*q+3].x += a.w * w[r].x; acc[4*q+3].y += a.w * w[r].y;
                }
            }
        }
#pragma unroll
        for (int b = 0; b < BN; b++)
            *(float2*)&y_part[(size_t)c * (BN * DD) + (size_t)b * DD + n0] = acc[b];
    }
}

// ---------------------------------------------------------------------------
// mags[b][u] = c^T S_u c ; coeff_full write; masked atomicMax argmax into best[s][b]
// key = (float_bits(mag) << 6) | (31-u)  -> on ties, lowest u wins (matches ref)
__global__ __launch_bounds__(128) void k_magsmax(const float* __restrict__ coeff_part,
                                                 const float* __restrict__ S,
                                                 float* __restrict__ coeff_full,
                                                 unsigned long long* __restrict__ best,
                                                 const int* __restrict__ routes, int s) {
    int b = blockIdx.x >> 5;
    int u = blockIdx.x & 31;
    int t = threadIdx.x;

    __shared__ int s_used;
    __shared__ float lc[BASISK];
    __shared__ float red[BASISK];

    if (t == 0) {
        int used = 0;
        for (int j = 0; j < s; j++) used |= (routes[b * DEPTH + j] == u);
        s_used = used;
    }
    __syncthreads();
    if (s_used) return;

    float cv = 0.f;
#pragma unroll
    for (int fc = 0; fc < 8; fc++)
        cv += coeff_part[((size_t)(fc * BN + b) * NU + u) * BASISK + t];
    lc[t] = cv;
    coeff_full[((size_t)b * NU + u) * BASISK + t] = cv;
    __syncthreads();

    float v = 0.f;
    const float* Sp = S + (size_t)u * BASISK * BASISK + t;
#pragma unroll 8
    for (int i = 0; i < BASISK; i++) v += Sp[(size_t)i * BASISK] * lc[i];

    red[t] = v * cv;
    __syncthreads();
    for (int st = 64; st > 0; st >>= 1) {
        if (t < st) red[t] += red[t + st];
        __syncthreads();
    }
    if (t == 0) {
        float mag = fmaxf(red[0], 0.f);
        unsigned long long key =
            ((unsigned long long)__float_as_uint(mag) << 6) |
            (unsigned long long)(31 - u);
        atomicMax(best + (size_t)s * BN + b, key);
    }
}

// ---------------------------------------------------------------------------
// Fused tail:
//   blocks [0,nMatP): y-reduce + bias[sel] + tanh -> xfT_next + P-matmul partial
//     decomposed (c, bh): each block owns 8 exclusive b columns -> no duplication
//   blocks [nMatP, nMatP+64): residual out_acc += h_full - B_sel c_sel; record route
__global__ __launch_bounds__(256) void k_tail(const float* __restrict__ y_part,
                                              const float* __restrict__ bias,
                                              const unsigned long long* __restrict__ best,
                                              const float* __restrict__ P,
                                              float* __restrict__ xfT_next,
                                              float* __restrict__ h_part,
                                              const float* __restrict__ h_full,
                                              const float* __restrict__ coeff_full,
                                              const float* __restrict__ basis,
                                              float* __restrict__ out_acc,
                                              int* __restrict__ routes,
                                              int s, int nMatP) {
    int t = threadIdx.x;

    if ((int)blockIdx.x < nMatP) {
        __shared__ __align__(16) float lxf[KCH_H * LXF_LD];   // 9.2 KB
        int bh = blockIdx.x & 1;
        int c  = blockIdx.x >> 1;
        int kbase = c * KCH_H;

        // stage: reduce y partials + bias + tanh (each element exactly once)
        for (int j = t; j < KCH_H * 8; j += 256) {
            int b_l = j / KCH_H;
            int fl  = j - b_l * KCH_H;
            int b   = bh * 8 + b_l;
            float sum = 0.f;
            const float* yp = y_part + (size_t)b * DD + kbase + fl;
#pragma unroll 4
            for (int cc = 0; cc < KC_Y; cc++) sum += yp[(size_t)cc * (BN * DD)];
            int u = 31 - (int)(best[(size_t)s * BN + b] & 63ull);
            float v = tanhf(sum + bias[(size_t)u * DD + kbase + fl]);
            lxf[fl * LXF_LD + b_l] = v;
            xfT_next[(size_t)(kbase + fl) * BN + b] = v;
        }
        __syncthreads();

        int f0 = t * 4;
        float acc[8][4] = {};
        const float* wp = P + (size_t)kbase * HASHF + f0;
        for (int kl = 0; kl < KCH_H; kl++) {
            float4 w = *(const float4*)(wp + (size_t)kl * HASHF);
            const float4* xv = (const float4*)&lxf[kl * LXF_LD];
            float4 x0 = xv[0], x1 = xv[1];
            float xb[8] = {x0.x, x0.y, x0.z, x0.w, x1.x, x1.y, x1.z, x1.w};
#pragma unroll
            for (int b = 0; b < 8; b++) {
                acc[b][0] += xb[b] * w.x; acc[b][1] += xb[b] * w.y;
                acc[b][2] += xb[b] * w.z; acc[b][3] += xb[b] * w.w;
            }
        }
        float* hp = h_part + (size_t)c * (BN * HASHF) + (size_t)(bh * 8) * HASHF + f0;
#pragma unroll
        for (int b = 0; b < 8; b++)
            *(float4*)&hp[(size_t)b * HASHF] =
                make_float4(acc[b][0], acc[b][1], acc[b][2], acc[b][3]);
    } else {
        int rid = blockIdx.x - nMatP;
        int b   = rid >> 2;
        int fq  = rid & 3;
        __shared__ float lc[BASISK];

        int u = 31 - (int)(best[(size_t)s * BN + b] & 63ull);
        if (t < BASISK) lc[t] = coeff_full[((size_t)b * NU + u) * BASISK + t];
        if (t == 0 && fq == 0) routes[b * DEPTH + s] = u;
        __syncthreads();

        int f = fq * 256 + t;
        float hv = h_full[(size_t)b * HASHF + f];
        const float4* br = (const float4*)&basis[((size_t)u * HASHF + f) * BASISK];
        const float4* cr = (const float4*)lc;
        float dot = 0.f;
#pragma unroll
        for (int j = 0; j < 32; j++) {
            float4 bv = br[j], c4 = cr[j];
            dot += bv.x * c4.x + bv.y * c4.y + bv.z * c4.z + bv.w * c4.w;
        }
        out_acc[b * HASHF + f] += hv - dot;
    }
}

// ---------------------------------------------------------------------------
__global__ __launch_bounds__(256) void k_out(const float* __restrict__ out_acc,
                                             const int* __restrict__ routes,
                                             float* __restrict__ o, int n) {
    int i = blockIdx.x * 256 + threadIdx.x;
    if (i >= n) return;
    if (i < BN * HASHF) o[i] = out_acc[i];
    else o[i] = (float)routes[i - BN * HASHF];
}

// ---------------------------------------------------------------------------
extern "C" void kernel_launch(void* const* d_in, const int* in_sizes, int n_in,
                              void* d_out, int out_size, void* d_ws, size_t ws_size,
                              hipStream_t stream) {
    const float* x     = (const float*)d_in[0];
    const float* P     = (const float*)d_in[1];
    const float* basis = (const float*)d_in[2];
    const float* Wt    = (const float*)d_in[3];
    const float* bias  = (const float*)d_in[4];
    float* out = (float*)d_out;

    float* w = (float*)d_ws;
    size_t off = 0;
    auto alloc = [&](size_t nf) { float* p = w + off; off += nf; return p; };

    float* xfT0       = alloc((size_t)DD * BN);
    float* xfT1       = alloc((size_t)DD * BN);
    float* out_acc    = alloc(BN * HASHF);
    unsigned long long* best = (unsigned long long*)alloc(DEPTH * BN * 2); // 8B each
    float* coeff_part = alloc((size_t)8 * BN * NU * BASISK);
    float* coeff_full = alloc((size_t)BN * NU * BASISK);
    float* h_full     = alloc((size_t)BN * HASHF);
    float* S          = alloc((size_t)NU * BASISK * BASISK);
    int*   routes     = (int*)alloc(BN * DEPTH);
    float* y_part     = alloc((size_t)KC_Y * BN * DD);
    float* h_part     = alloc((size_t)KC_H * BN * HASHF);
    (void)ws_size;

    // zero out_acc + best (contiguous)
    hipMemsetAsync(out_acc, 0,
                   (size_t)BN * HASHF * sizeof(float) +
                   (size_t)DEPTH * BN * sizeof(unsigned long long), stream);

    k_transpose<<<(BN * DD) / 256, 256, 0, stream>>>(x, xfT0);
    k_S<<<NU * 8, 128, 0, stream>>>(basis, S);
    k_matP<<<2 * KC_H, 256, 0, stream>>>(xfT0, P, h_part);

    for (int s = 0; s < DEPTH; s++) {
        float* cur = (s & 1) ? xfT1 : xfT0;
        float* nxt = (s & 1) ? xfT0 : xfT1;

        int nWt = (s < DEPTH - 1) ? 24 * KC_Y : 0;       // skip dead Wt stream at s=15
        k_big<<<128 + nWt, 256, 0, stream>>>(cur, Wt, y_part, h_part, basis,
                                             coeff_part, h_full);
        k_magsmax<<<BN * NU, 128, 0, stream>>>(coeff_part, S, coeff_full, best,
                                               routes, s);
        int nMatP = (s < DEPTH - 1) ? 2 * KC_H : 0;      // residual-only at s=15
        k_tail<<<nMatP + 64, 256, 0, stream>>>(y_part, bias, best, P, nxt, h_part,
                                               h_full, coeff_full, basis, out_acc,
                                               routes, s, nMatP);
    }

    k_out<<<(BN * HASHF + BN * DEPTH + 255) / 256, 256, 0, stream>>>(out_acc, routes,
                                                                     out, out_size);
}